// Round 3
// baseline (1312.125 us; speedup 1.0000x reference)
//
#include <hip/hip_runtime.h>

#define RN      128
#define START_T 126
#define END_T   127
#define NSEQ    16

typedef short v8s __attribute__((ext_vector_type(8)));   // 8 x bf16 MFMA A/B frag
typedef float v4f __attribute__((ext_vector_type(4)));   // 4 x f32 MFMA C/D frag

__device__ __forceinline__ unsigned short f2bf(float f){
    unsigned u = __float_as_uint(f);
    u += 0x7fffu + ((u>>16)&1u);
    return (unsigned short)(u>>16);
}
__device__ __forceinline__ float bf2f(unsigned short s){
    return __uint_as_float(((unsigned)s)<<16);
}
__device__ __forceinline__ unsigned cvt_pk(float lo, float hi){
    unsigned r;
    asm("v_cvt_pk_bf16_f32 %0, %1, %2" : "=v"(r) : "v"(lo), "v"(hi));
    return r;
}
__device__ __forceinline__ float4 exp4(float4 v){
    float4 e; e.x=__expf(v.x); e.y=__expf(v.y); e.z=__expf(v.z); e.w=__expf(v.w); return e;
}
__device__ __forceinline__ v8s mk8(unsigned d0, unsigned d1, unsigned d2, unsigned d3){
    union { unsigned u[4]; v8s v; } U;
    U.u[0]=d0; U.u[1]=d1; U.u[2]=d2; U.u[3]=d3; return U.v;
}

// One recurrence step, phase PH = t&3 (compile-time).
// Permuted-A trick: tile T computes output states pi(T,m)=32(T&3)+8(m>>2)+4(T>>2)+(m&3),
// so lane (c,q) ends the step holding exactly the states {32a+8q+u} it needs as
// next-step B-operand k-values: p never leaves the lane. No LDS, no barriers.
template<int PH>
__device__ __forceinline__ void stepf(const v8s (&Ef)[8][4],
                                      v8s &Bf0, v8s &Bf1, v8s &Bf2, v8s &Bf3,
                                      const float4 &S0, const float4 &S1,
                                      const float4 &S2, const float4 &S3,
                                      const float4 &S4, const float4 &S5,
                                      const float4 &S6, const float4 &S7,
                                      float &logscale, float &mxf, float &invv)
{
    // emissions: ev for tile T comes from slot (T&3)*2 + (T>>2)
    float4 e0 = exp4(S0), e1 = exp4(S2), e2 = exp4(S4), e3 = exp4(S6);
    float4 e4 = exp4(S1), e5 = exp4(S3), e6 = exp4(S5), e7 = exp4(S7);

    v4f a0={0.f,0.f,0.f,0.f}, a1={0.f,0.f,0.f,0.f}, a2={0.f,0.f,0.f,0.f}, a3={0.f,0.f,0.f,0.f};
    v4f a4={0.f,0.f,0.f,0.f}, a5={0.f,0.f,0.f,0.f}, a6={0.f,0.f,0.f,0.f}, a7={0.f,0.f,0.f,0.f};

    a0 = __builtin_amdgcn_mfma_f32_16x16x32_bf16(Ef[0][0], Bf0, a0, 0,0,0);
    a1 = __builtin_amdgcn_mfma_f32_16x16x32_bf16(Ef[1][0], Bf0, a1, 0,0,0);
    a2 = __builtin_amdgcn_mfma_f32_16x16x32_bf16(Ef[2][0], Bf0, a2, 0,0,0);
    a3 = __builtin_amdgcn_mfma_f32_16x16x32_bf16(Ef[3][0], Bf0, a3, 0,0,0);
    a4 = __builtin_amdgcn_mfma_f32_16x16x32_bf16(Ef[4][0], Bf0, a4, 0,0,0);
    a5 = __builtin_amdgcn_mfma_f32_16x16x32_bf16(Ef[5][0], Bf0, a5, 0,0,0);
    a6 = __builtin_amdgcn_mfma_f32_16x16x32_bf16(Ef[6][0], Bf0, a6, 0,0,0);
    a7 = __builtin_amdgcn_mfma_f32_16x16x32_bf16(Ef[7][0], Bf0, a7, 0,0,0);

    a0 = __builtin_amdgcn_mfma_f32_16x16x32_bf16(Ef[0][1], Bf1, a0, 0,0,0);
    a1 = __builtin_amdgcn_mfma_f32_16x16x32_bf16(Ef[1][1], Bf1, a1, 0,0,0);
    a2 = __builtin_amdgcn_mfma_f32_16x16x32_bf16(Ef[2][1], Bf1, a2, 0,0,0);
    a3 = __builtin_amdgcn_mfma_f32_16x16x32_bf16(Ef[3][1], Bf1, a3, 0,0,0);
    a4 = __builtin_amdgcn_mfma_f32_16x16x32_bf16(Ef[4][1], Bf1, a4, 0,0,0);
    a5 = __builtin_amdgcn_mfma_f32_16x16x32_bf16(Ef[5][1], Bf1, a5, 0,0,0);
    a6 = __builtin_amdgcn_mfma_f32_16x16x32_bf16(Ef[6][1], Bf1, a6, 0,0,0);
    a7 = __builtin_amdgcn_mfma_f32_16x16x32_bf16(Ef[7][1], Bf1, a7, 0,0,0);

    a0 = __builtin_amdgcn_mfma_f32_16x16x32_bf16(Ef[0][2], Bf2, a0, 0,0,0);
    a1 = __builtin_amdgcn_mfma_f32_16x16x32_bf16(Ef[1][2], Bf2, a1, 0,0,0);
    a2 = __builtin_amdgcn_mfma_f32_16x16x32_bf16(Ef[2][2], Bf2, a2, 0,0,0);
    a3 = __builtin_amdgcn_mfma_f32_16x16x32_bf16(Ef[3][2], Bf2, a3, 0,0,0);
    a4 = __builtin_amdgcn_mfma_f32_16x16x32_bf16(Ef[4][2], Bf2, a4, 0,0,0);
    a5 = __builtin_amdgcn_mfma_f32_16x16x32_bf16(Ef[5][2], Bf2, a5, 0,0,0);
    a6 = __builtin_amdgcn_mfma_f32_16x16x32_bf16(Ef[6][2], Bf2, a6, 0,0,0);
    a7 = __builtin_amdgcn_mfma_f32_16x16x32_bf16(Ef[7][2], Bf2, a7, 0,0,0);

    a0 = __builtin_amdgcn_mfma_f32_16x16x32_bf16(Ef[0][3], Bf3, a0, 0,0,0);
    a1 = __builtin_amdgcn_mfma_f32_16x16x32_bf16(Ef[1][3], Bf3, a1, 0,0,0);
    a2 = __builtin_amdgcn_mfma_f32_16x16x32_bf16(Ef[2][3], Bf3, a2, 0,0,0);
    a3 = __builtin_amdgcn_mfma_f32_16x16x32_bf16(Ef[3][3], Bf3, a3, 0,0,0);
    a4 = __builtin_amdgcn_mfma_f32_16x16x32_bf16(Ef[4][3], Bf3, a4, 0,0,0);
    a5 = __builtin_amdgcn_mfma_f32_16x16x32_bf16(Ef[5][3], Bf3, a5, 0,0,0);
    a6 = __builtin_amdgcn_mfma_f32_16x16x32_bf16(Ef[6][3], Bf3, a6, 0,0,0);
    a7 = __builtin_amdgcn_mfma_f32_16x16x32_bf16(Ef[7][3], Bf3, a7, 0,0,0);

    if (PH == 2) { invv = 1.0f / mxf; logscale += __logf(mxf); }

    float4 o0, o1, o2, o3, o4, o5, o6, o7;
    #define OT(o, A, E) o.x=A[0]*E.x; o.y=A[1]*E.y; o.z=A[2]*E.z; o.w=A[3]*E.w;
    OT(o0,a0,e0) OT(o1,a1,e1) OT(o2,a2,e2) OT(o3,a3,e3)
    OT(o4,a4,e4) OT(o5,a5,e5) OT(o6,a6,e6) OT(o7,a7,e7)
    #undef OT
    if (PH == 2) {
        #define SC(o) o.x*=invv; o.y*=invv; o.z*=invv; o.w*=invv;
        SC(o0) SC(o1) SC(o2) SC(o3) SC(o4) SC(o5) SC(o6) SC(o7)
        #undef SC
    }
    if (PH == 1) {   // per-seq (per-column) running max; applied stale-by-one at PH==2
        float vmax = 0.f;
        #define MX(o) vmax = fmaxf(vmax, fmaxf(fmaxf(o.x,o.y), fmaxf(o.z,o.w)));
        MX(o0) MX(o1) MX(o2) MX(o3) MX(o4) MX(o5) MX(o6) MX(o7)
        #undef MX
        float m1 = fmaxf(vmax, __shfl_xor(vmax, 16, 64));
        mxf = fmaxf(m1, __shfl_xor(m1, 32, 64));
    }

    // repack as next step's B-frags (same lane): Bf[cc][j] = state 32cc+8q+j
    //   j<4 -> tile T=cc reg j ; j>=4 -> tile T=cc+4 reg j-4
    Bf0 = mk8(cvt_pk(o0.x,o0.y), cvt_pk(o0.z,o0.w), cvt_pk(o4.x,o4.y), cvt_pk(o4.z,o4.w));
    Bf1 = mk8(cvt_pk(o1.x,o1.y), cvt_pk(o1.z,o1.w), cvt_pk(o5.x,o5.y), cvt_pk(o5.z,o5.w));
    Bf2 = mk8(cvt_pk(o2.x,o2.y), cvt_pk(o2.z,o2.w), cvt_pk(o6.x,o6.y), cvt_pk(o6.z,o6.w));
    Bf3 = mk8(cvt_pk(o3.x,o3.y), cvt_pk(o3.z,o3.w), cvt_pk(o7.x,o7.y), cvt_pk(o7.z,o7.w));
}

// slot i = a*2+b holds float4 at state offset 32a+4b (+8q): emission prefetch,
// issued 4 steps ahead of use (~>=1200 cy slack vs ~900 cy HBM latency)
#define ISSUE(S, tt_) {                                                        \
    int t_ = (tt_); if (t_ >= L) t_ = L - 1;                                   \
    const float* xp_ = Xb + (size_t)t_ * RN + 8 * q;                           \
    S##0 = *(const float4*)(xp_ +   0); S##1 = *(const float4*)(xp_ +   4);    \
    S##2 = *(const float4*)(xp_ +  32); S##3 = *(const float4*)(xp_ +  36);    \
    S##4 = *(const float4*)(xp_ +  64); S##5 = *(const float4*)(xp_ +  68);    \
    S##6 = *(const float4*)(xp_ +  96); S##7 = *(const float4*)(xp_ + 100); }

// 16 blocks x 1 wave. Lane (c,q): c = sequence column, q = k/row quad.
// Entire recurrence is register-resident; no __shared__, no barriers.
__global__ __attribute__((amdgpu_flat_work_group_size(64,64), amdgpu_waves_per_eu(1,1)))
void crf_nll_kernel(const float* __restrict__ X,
                    const int*   __restrict__ y,
                    const float* __restrict__ trans,
                    float* __restrict__ out, int L, int B)
{
    const int g    = blockIdx.x;
    const int lane = threadIdx.x & 63;
    const int c    = lane & 15;
    const int q    = lane >> 4;
    const int b0   = g * NSEQ;

    int bseq = b0 + c; if (bseq >= B) bseq = B - 1;
    const float* Xb = X + (size_t)bseq * L * RN;
    const int*   yb = y + (size_t)bseq * L;

    // ---------------- gold path (4 t-stripes per seq across quads) ----------------
    float gold = 0.f;
    for (int t = q; t < L; t += 4) {
        int yt = yb[t];
        int yp = t ? yb[t-1] : START_T;
        gold += trans[yt*RN + yp] + Xb[(size_t)t*RN + yt];
    }
    if (q == 3) gold += trans[END_T*RN + yb[L-1]];
    gold += __shfl_xor(gold, 16, 64);
    gold += __shfl_xor(gold, 32, 64);

    // ---------------- Ef: permuted exp(trans) A-frags ----------------
    // tile T row for m=c: pi = 32(T&3) + 8(c>>2) + 4(T>>2) + (c&3)
    v8s Ef[8][4];
    #pragma unroll
    for (int T = 0; T < 8; ++T) {
        const int row = 32*(T&3) + 8*(c>>2) + 4*(T>>2) + (c&3);
        #pragma unroll
        for (int cc = 0; cc < 4; ++cc) {
            const float* tr = trans + (size_t)row*RN + 32*cc + 8*q;
            v8s v;
            #pragma unroll
            for (int j = 0; j < 8; ++j) v[j] = (short)f2bf(__expf(tr[j]));
            Ef[T][cc] = v;
        }
    }

    // ---------------- p0 = one-hot(START=126): cc=3, q=3, j=6 ----------------
    v8s Bf0, Bf1, Bf2, Bf3;
    {
        v8s z;
        #pragma unroll
        for (int j = 0; j < 8; ++j) z[j] = 0;
        Bf0 = z; Bf1 = z; Bf2 = z; Bf3 = z;
        if (q == 3) Bf3 = mk8(0u, 0u, 0u, 0x00003F80u);
    }

    // ---------------- emission prefetch ring (4 slots x 8 float4) ----------------
    float4 SA0,SA1,SA2,SA3,SA4,SA5,SA6,SA7;
    float4 SB0,SB1,SB2,SB3,SB4,SB5,SB6,SB7;
    float4 SC0,SC1,SC2,SC3,SC4,SC5,SC6,SC7;
    float4 SD0,SD1,SD2,SD3,SD4,SD5,SD6,SD7;
    ISSUE(SA, 0) ISSUE(SB, 1) ISSUE(SC, 2) ISSUE(SD, 3)

    float logscale = 0.f, mxf = 1.f, invv = 1.f;

    // ---------------- main recurrence (L % 4 == 0; L=1024 here) ----------------
    for (int tt = 0; tt < L; tt += 4) {
        stepf<0>(Ef, Bf0,Bf1,Bf2,Bf3, SA0,SA1,SA2,SA3,SA4,SA5,SA6,SA7, logscale, mxf, invv);
        ISSUE(SA, tt + 4)
        stepf<1>(Ef, Bf0,Bf1,Bf2,Bf3, SB0,SB1,SB2,SB3,SB4,SB5,SB6,SB7, logscale, mxf, invv);
        ISSUE(SB, tt + 5)
        stepf<2>(Ef, Bf0,Bf1,Bf2,Bf3, SC0,SC1,SC2,SC3,SC4,SC5,SC6,SC7, logscale, mxf, invv);
        ISSUE(SC, tt + 6)
        stepf<3>(Ef, Bf0,Bf1,Bf2,Bf3, SD0,SD1,SD2,SD3,SD4,SD5,SD6,SD7, logscale, mxf, invv);
        ISSUE(SD, tt + 7)
    }

    // ---------------- logZ: sum p_L[s] * exp(trans[END,s]) per seq ----------------
    float zacc = 0.f;
    #pragma unroll
    for (int cc = 0; cc < 4; ++cc) {
        const v8s pv = (cc==0) ? Bf0 : (cc==1) ? Bf1 : (cc==2) ? Bf2 : Bf3;
        #pragma unroll
        for (int j = 0; j < 8; ++j) {
            const int k = 32*cc + 8*q + j;
            zacc += bf2f((unsigned short)pv[j]) * __expf(trans[END_T*RN + k]);
        }
    }
    zacc += __shfl_xor(zacc, 16, 64);
    zacc += __shfl_xor(zacc, 32, 64);

    if (q == 0 && (b0 + c) < B)
        out[b0 + c] = logscale + __logf(zacc) - gold;
}

extern "C" void kernel_launch(void* const* d_in, const int* in_sizes, int n_in,
                              void* d_out, int out_size, void* d_ws, size_t ws_size,
                              hipStream_t stream) {
    const float* X     = (const float*)d_in[0];
    const int*   y     = (const int*)d_in[1];
    const float* trans = (const float*)d_in[2];
    float*       out   = (float*)d_out;

    const int B = out_size;            // 256
    const int L = in_sizes[1] / B;     // 1024

    const int blocks = (B + NSEQ - 1) / NSEQ;   // 16
    crf_nll_kernel<<<dim3(blocks), dim3(64), 0, stream>>>(X, y, trans, out, L, B);
}

// Round 4
// 629.342 us; speedup vs baseline: 2.0849x; 2.0849x over previous
//
#include <hip/hip_runtime.h>

#define RN      128
#define START_T 126
#define END_T   127
#define NSEQ    16
#define PBS     272              // pbuf row stride (bytes): 16B-aligned, 17*16 -> bank-spread
#define PHALF   (NSEQ*PBS)      // one p buffer (4352 B)

typedef short v8s __attribute__((ext_vector_type(8)));   // 8 x bf16 MFMA A/B frag
typedef float v4f __attribute__((ext_vector_type(4)));   // 4 x f32 MFMA C/D frag

__device__ __forceinline__ unsigned short f2bf(float f){
    unsigned u = __float_as_uint(f);
    u += 0x7fffu + ((u>>16)&1u);
    return (unsigned short)(u>>16);
}
__device__ __forceinline__ float bf2f(unsigned short s){
    return __uint_as_float(((unsigned)s)<<16);
}
__device__ __forceinline__ unsigned cvt_pk(float lo, float hi){
    unsigned r;
    asm("v_cvt_pk_bf16_f32 %0, %1, %2" : "=v"(r) : "v"(lo), "v"(hi));
    return r;
}
__device__ __forceinline__ unsigned pkmax_u16(unsigned a, unsigned b){
    unsigned r;
    asm("v_pk_max_u16 %0, %1, %2" : "=v"(r) : "v"(a), "v"(b));
    return r;
}
__device__ __forceinline__ float4 exp4(float4 v){
    float4 e; e.x=__expf(v.x); e.y=__expf(v.y); e.z=__expf(v.z); e.w=__expf(v.w); return e;
}

// One step. 4 waves, wave w owns tiles {2w, 2w+1}; 8 MFMAs/wave on its own SIMD
// (per-SIMD MFMA throughput ~19cy each; spreading is the round-3 lesson).
// Permuted-A: tile T row m=c -> state 32(T&3)+8q+4(T>>2)+(reg i), so the wave's
// 8 outputs/lane are two aligned 4-state runs of the B layout: 2 ds_write_b64.
// Barrier = lgkmcnt(0)+s_barrier only: global prefetch ring stays in flight.
template<int PH>
__device__ __forceinline__ void stepf(const v8s (&Ef)[2][4],
                                      char* prb, char* pwb,
                                      const int (&prd)[4], const int (&pwr)[2],
                                      const float4& S0, const float4& S1,
                                      float& logscale, float& mxf, float& invv)
{
    v8s B0 = *(const v8s*)(prb + prd[0]);
    v8s B1 = *(const v8s*)(prb + prd[1]);
    v8s B2 = *(const v8s*)(prb + prd[2]);
    v8s B3 = *(const v8s*)(prb + prd[3]);

    if (PH == 1) {
        // per-seq max from the B view: lane (c,q) holds 32 values of seq c;
        // quads give the other 96 -> 2 shfl_xor. All waves compute identically.
        union U8 { v8s v; unsigned u[4]; };
        U8 ua, ub, uc, ud; ua.v = B0; ub.v = B1; uc.v = B2; ud.v = B3;
        unsigned m0 = pkmax_u16(ua.u[0], ua.u[1]);
        unsigned m1 = pkmax_u16(ua.u[2], ua.u[3]);
        unsigned m2 = pkmax_u16(ub.u[0], ub.u[1]);
        unsigned m3 = pkmax_u16(ub.u[2], ub.u[3]);
        unsigned m4 = pkmax_u16(uc.u[0], uc.u[1]);
        unsigned m5 = pkmax_u16(uc.u[2], uc.u[3]);
        unsigned m6 = pkmax_u16(ud.u[0], ud.u[1]);
        unsigned m7 = pkmax_u16(ud.u[2], ud.u[3]);
        m0 = pkmax_u16(m0, m1); m2 = pkmax_u16(m2, m3);
        m4 = pkmax_u16(m4, m5); m6 = pkmax_u16(m6, m7);
        m0 = pkmax_u16(m0, m2); m4 = pkmax_u16(m4, m6);
        m0 = pkmax_u16(m0, m4);
        unsigned lo = m0 & 0xffffu, hi = m0 >> 16;
        unsigned mm = (lo > hi) ? lo : hi;            // bf16 >= 0: bit order == value order
        float f = __uint_as_float(mm << 16);
        f = fmaxf(f, __shfl_xor(f, 16, 64));
        f = fmaxf(f, __shfl_xor(f, 32, 64));
        mxf = f;
    }
    if (PH == 2) { invv = 1.0f / mxf; logscale += __logf(mxf); }

    float4 e0 = exp4(S0), e1 = exp4(S1);   // emissions for this wave's 2 tiles

    v4f a0 = {0.f,0.f,0.f,0.f};
    v4f a1 = {0.f,0.f,0.f,0.f};
    a0 = __builtin_amdgcn_mfma_f32_16x16x32_bf16(Ef[0][0], B0, a0, 0,0,0);
    a1 = __builtin_amdgcn_mfma_f32_16x16x32_bf16(Ef[1][0], B0, a1, 0,0,0);
    a0 = __builtin_amdgcn_mfma_f32_16x16x32_bf16(Ef[0][1], B1, a0, 0,0,0);
    a1 = __builtin_amdgcn_mfma_f32_16x16x32_bf16(Ef[1][1], B1, a1, 0,0,0);
    a0 = __builtin_amdgcn_mfma_f32_16x16x32_bf16(Ef[0][2], B2, a0, 0,0,0);
    a1 = __builtin_amdgcn_mfma_f32_16x16x32_bf16(Ef[1][2], B2, a1, 0,0,0);
    a0 = __builtin_amdgcn_mfma_f32_16x16x32_bf16(Ef[0][3], B3, a0, 0,0,0);
    a1 = __builtin_amdgcn_mfma_f32_16x16x32_bf16(Ef[1][3], B3, a1, 0,0,0);

    float o00 = a0[0]*e0.x, o01 = a0[1]*e0.y, o02 = a0[2]*e0.z, o03 = a0[3]*e0.w;
    float o10 = a1[0]*e1.x, o11 = a1[1]*e1.y, o12 = a1[2]*e1.z, o13 = a1[3]*e1.w;
    if (PH == 2) {
        o00*=invv; o01*=invv; o02*=invv; o03*=invv;
        o10*=invv; o11*=invv; o12*=invv; o13*=invv;
    }
    uint2 d0, d1;
    d0.x = cvt_pk(o00,o01); d0.y = cvt_pk(o02,o03);
    d1.x = cvt_pk(o10,o11); d1.y = cvt_pk(o12,o13);
    *(uint2*)(pwb + pwr[0]) = d0;
    *(uint2*)(pwb + pwr[1]) = d1;

    asm volatile("s_waitcnt lgkmcnt(0)" ::: "memory");  // drain LDS (reads+writes) only
    __builtin_amdgcn_s_barrier();
    __builtin_amdgcn_sched_barrier(0);
}

// emission prefetch: wave's 2 tiles' states for step t_, 4-step distance
#define ISSUE(S0v, S1v, tt_) {                                   \
    int t_ = (tt_); if (t_ >= L) t_ = L - 1;                     \
    const float* xp_ = Xb + (size_t)t_ * RN;                     \
    S0v = *(const float4*)(xp_ + o0);                            \
    S1v = *(const float4*)(xp_ + o1); }

__global__ __launch_bounds__(256, 1)
void crf_nll_kernel(const float* __restrict__ X,
                    const int*   __restrict__ y,
                    const float* __restrict__ trans,
                    float* __restrict__ out, int L, int B)
{
    const int g    = blockIdx.x;
    const int tid  = threadIdx.x;
    const int w    = tid >> 6;
    const int lane = tid & 63;
    const int c    = lane & 15;     // MFMA column = sequence
    const int q    = lane >> 4;     // k/row quad
    const int b0   = g * NSEQ;

    __shared__ __align__(16) char  pb[2*PHALF];
    __shared__ float goldsh[NSEQ];

    int bseq = b0 + c; if (bseq >= B) bseq = B - 1;
    const float* Xb = X + (size_t)bseq * L * RN;
    const int*   yb = y + (size_t)bseq * L;

    // ---------------- init p buffers + goldsh ----------------
    if (tid < NSEQ) goldsh[tid] = 0.f;
    {
        int* pz = (int*)pb;
        for (int i = tid; i < (2*PHALF)/4; i += 256) pz[i] = 0;
    }
    __syncthreads();
    if (tid < NSEQ)   // p0[n][START]=1.0 (bf16), buffer 0
        *(unsigned short*)(pb + tid*PBS + 2*START_T) = (unsigned short)0x3F80;

    // ---------------- gold path: 16 t-stripes (w,q) per seq ----------------
    {
        float gacc = 0.f;
        for (int t = 4*w + q; t < L; t += 16) {
            int yt = yb[t];
            int yp = t ? yb[t-1] : START_T;
            gacc += trans[yt*RN + yp] + Xb[(size_t)t*RN + yt];
        }
        if (w == 0 && q == 0) gacc += trans[END_T*RN + yb[L-1]];
        gacc += __shfl_xor(gacc, 16, 64);
        gacc += __shfl_xor(gacc, 32, 64);
        if (q == 0) atomicAdd(&goldsh[c], gacc);
    }

    // ---------------- Ef: this wave's 2 permuted exp(trans) A-tiles ----------------
    // tile T row for m=c: 32(T&3) + 8(c>>2) + 4(T>>2) + (c&3)
    const int T0 = 2*w, T1 = 2*w + 1;
    v8s Ef[2][4];
    #pragma unroll
    for (int i = 0; i < 2; ++i) {
        const int T   = 2*w + i;
        const int row = 32*(T&3) + 8*(c>>2) + 4*(T>>2) + (c&3);
        #pragma unroll
        for (int cc = 0; cc < 4; ++cc) {
            const float* tr = trans + (size_t)row*RN + 32*cc + 8*q;
            v8s v;
            #pragma unroll
            for (int j = 0; j < 8; ++j) v[j] = (short)f2bf(__expf(tr[j]));
            Ef[i][cc] = v;
        }
    }

    // ---------------- LDS byte offsets ----------------
    int prd[4], pwr[2];
    #pragma unroll
    for (int cc = 0; cc < 4; ++cc)
        prd[cc] = c*PBS + 64*cc + 16*q;                      // read k=32cc+8q (16B)
    pwr[0] = c*PBS + 64*(T0&3) + 8*(T0>>2) + 16*q;           // write tiles' 4-state runs (8B)
    pwr[1] = c*PBS + 64*(T1&3) + 8*(T1>>2) + 16*q;
    // emission state offsets for the 2 tiles
    const int o0 = 32*(T0&3) + 4*(T0>>2) + 8*q;
    const int o1 = 32*(T1&3) + 4*(T1>>2) + 8*q;

    __syncthreads();   // p0 + goldsh visible; ring primed after (no drain later)

    // ---------------- emission ring: 4 slots x 2 float4 ----------------
    float4 SA0,SA1, SB0,SB1, SC0,SC1, SD0,SD1;
    ISSUE(SA0,SA1, 0) ISSUE(SB0,SB1, 1) ISSUE(SC0,SC1, 2) ISSUE(SD0,SD1, 3)

    float logscale = 0.f, mxf = 1.f, invv = 1.f;

    const int L4 = L & ~3;
    for (int tt = 0; tt < L4; tt += 4) {
        stepf<0>(Ef, pb,         pb + PHALF, prd, pwr, SA0, SA1, logscale, mxf, invv);
        ISSUE(SA0,SA1, tt + 4)
        stepf<1>(Ef, pb + PHALF, pb,         prd, pwr, SB0, SB1, logscale, mxf, invv);
        ISSUE(SB0,SB1, tt + 5)
        stepf<2>(Ef, pb,         pb + PHALF, prd, pwr, SC0, SC1, logscale, mxf, invv);
        ISSUE(SC0,SC1, tt + 6)
        stepf<3>(Ef, pb + PHALF, pb,         prd, pwr, SD0, SD1, logscale, mxf, invv);
        ISSUE(SD0,SD1, tt + 7)
    }
    // generic tail (L % 4 != 0; not exercised at L=1024)
    for (int t = L4; t < L; ++t) {
        char* prb_ = pb + (t & 1)*PHALF;
        char* pwb_ = pb + ((t + 1) & 1)*PHALF;
        float4 s0 = *(const float4*)(Xb + (size_t)t*RN + o0);
        float4 s1 = *(const float4*)(Xb + (size_t)t*RN + o1);
        switch (t & 3) {
            case 0: stepf<0>(Ef, prb_, pwb_, prd, pwr, s0, s1, logscale, mxf, invv); break;
            case 1: stepf<1>(Ef, prb_, pwb_, prd, pwr, s0, s1, logscale, mxf, invv); break;
            case 2: stepf<2>(Ef, prb_, pwb_, prd, pwr, s0, s1, logscale, mxf, invv); break;
            default: stepf<3>(Ef, prb_, pwb_, prd, pwr, s0, s1, logscale, mxf, invv); break;
        }
    }

    // ---------------- logZ: B-frag view of p_L (lane (c,q): 32 vals of seq c) ----------------
    char* pf = pb + (L & 1)*PHALF;
    float zacc = 0.f;
    #pragma unroll
    for (int cc = 0; cc < 4; ++cc) {
        v8s pv = *(const v8s*)(pf + prd[cc]);
        #pragma unroll
        for (int j = 0; j < 8; ++j) {
            const int k = 32*cc + 8*q + j;
            zacc += bf2f((unsigned short)pv[j]) * __expf(trans[END_T*RN + k]);
        }
    }
    zacc += __shfl_xor(zacc, 16, 64);
    zacc += __shfl_xor(zacc, 32, 64);

    if (w == 0 && q == 0 && (b0 + c) < B)
        out[b0 + c] = logscale + __logf(zacc) - goldsh[c];
}

extern "C" void kernel_launch(void* const* d_in, const int* in_sizes, int n_in,
                              void* d_out, int out_size, void* d_ws, size_t ws_size,
                              hipStream_t stream) {
    const float* X     = (const float*)d_in[0];
    const int*   y     = (const int*)d_in[1];
    const float* trans = (const float*)d_in[2];
    float*       out   = (float*)d_out;

    const int B = out_size;            // 256
    const int L = in_sizes[1] / B;     // 1024

    const int blocks = (B + NSEQ - 1) / NSEQ;   // 16
    crf_nll_kernel<<<dim3(blocks), dim3(256), 0, stream>>>(X, y, trans, out, L, B);
}

// Round 5
// 588.774 us; speedup vs baseline: 2.2286x; 1.0689x over previous
//
#include <hip/hip_runtime.h>

#define RN      128
#define START_T 126
#define END_T   127
#define NSEQ    16
#define PBS     272              // pbuf row stride (bytes)
#define PHALF   (NSEQ*PBS)       // one p buffer (4352 B)

typedef short v8s __attribute__((ext_vector_type(8)));   // 8 x bf16 MFMA A/B frag
typedef float v4f __attribute__((ext_vector_type(4)));   // 4 x f32 MFMA C/D frag

__device__ __forceinline__ unsigned short f2bf(float f){
    unsigned u = __float_as_uint(f);
    u += 0x7fffu + ((u>>16)&1u);
    return (unsigned short)(u>>16);
}
__device__ __forceinline__ float bf2f(unsigned short s){
    return __uint_as_float(((unsigned)s)<<16);
}
__device__ __forceinline__ unsigned cvt_pk(float lo, float hi){
    unsigned r;
    asm("v_cvt_pk_bf16_f32 %0, %1, %2" : "=v"(r) : "v"(lo), "v"(hi));
    return r;
}
__device__ __forceinline__ unsigned pkmax_u16(unsigned a, unsigned b){
    unsigned r;
    asm("v_pk_max_u16 %0, %1, %2" : "=v"(r) : "v"(a), "v"(b));
    return r;
}
__device__ __forceinline__ float4 exp4(float4 v){
    float4 e; e.x=__expf(v.x); e.y=__expf(v.y); e.z=__expf(v.z); e.w=__expf(v.w); return e;
}

// One phase-step for one direction-wave. 8 waves/WG: waves 0-3 forward, 4-7 backward
// (2 waves/SIMD -> two independent latency chains overlap on each SIMD).
// Split-tree MFMA: 2x 2-deep chains + f32 add (shorter dep chain than 4-deep).
// Barrier = lgkmcnt(0) + s_barrier (+compiler memory fence): vmcnt ring survives.
template<int PH>
__device__ __forceinline__ void stepf(const v8s (&Ef)[2][4],
                                      char* prb, char* pwb,
                                      const int (&prd)[4], const int (&pwr)[2],
                                      const float4& S0, const float4& S1,
                                      bool act, bool emit,
                                      float& logscale, float& mxf, float& invv)
{
    if (act) {
        v8s B0 = *(const v8s*)(prb + prd[0]);
        v8s B1 = *(const v8s*)(prb + prd[1]);
        v8s B2 = *(const v8s*)(prb + prd[2]);
        v8s B3 = *(const v8s*)(prb + prd[3]);

        if (PH == 1) {   // per-seq max over the B view (lane (c,q): 32 vals; quads via shfl)
            union U8 { v8s v; unsigned u[4]; };
            U8 ua, ub, uc, ud; ua.v = B0; ub.v = B1; uc.v = B2; ud.v = B3;
            unsigned m0 = pkmax_u16(ua.u[0], ua.u[1]);
            unsigned m1 = pkmax_u16(ua.u[2], ua.u[3]);
            unsigned m2 = pkmax_u16(ub.u[0], ub.u[1]);
            unsigned m3 = pkmax_u16(ub.u[2], ub.u[3]);
            unsigned m4 = pkmax_u16(uc.u[0], uc.u[1]);
            unsigned m5 = pkmax_u16(uc.u[2], uc.u[3]);
            unsigned m6 = pkmax_u16(ud.u[0], ud.u[1]);
            unsigned m7 = pkmax_u16(ud.u[2], ud.u[3]);
            m0 = pkmax_u16(m0, m1); m2 = pkmax_u16(m2, m3);
            m4 = pkmax_u16(m4, m5); m6 = pkmax_u16(m6, m7);
            m0 = pkmax_u16(m0, m2); m4 = pkmax_u16(m4, m6);
            m0 = pkmax_u16(m0, m4);
            unsigned lo = m0 & 0xffffu, hi = m0 >> 16;
            unsigned mm = (lo > hi) ? lo : hi;     // bf16 >= 0: bit order == value order
            float f = __uint_as_float(mm << 16);
            f = fmaxf(f, __shfl_xor(f, 16, 64));
            f = fmaxf(f, __shfl_xor(f, 32, 64));
            mxf = f;
        }
        if (PH == 2) { invv = 1.0f / mxf; logscale += __logf(mxf); }

        float4 e0, e1;
        if (emit) { e0 = exp4(S0); e1 = exp4(S1); }
        else      { e0.x=e0.y=e0.z=e0.w=1.f; e1 = e0; }   // bwd final step: raw r

        v4f a0l = {0.f,0.f,0.f,0.f}, a0h = {0.f,0.f,0.f,0.f};
        v4f a1l = {0.f,0.f,0.f,0.f}, a1h = {0.f,0.f,0.f,0.f};
        a0l = __builtin_amdgcn_mfma_f32_16x16x32_bf16(Ef[0][0], B0, a0l, 0,0,0);
        a0h = __builtin_amdgcn_mfma_f32_16x16x32_bf16(Ef[0][2], B2, a0h, 0,0,0);
        a1l = __builtin_amdgcn_mfma_f32_16x16x32_bf16(Ef[1][0], B0, a1l, 0,0,0);
        a1h = __builtin_amdgcn_mfma_f32_16x16x32_bf16(Ef[1][2], B2, a1h, 0,0,0);
        a0l = __builtin_amdgcn_mfma_f32_16x16x32_bf16(Ef[0][1], B1, a0l, 0,0,0);
        a0h = __builtin_amdgcn_mfma_f32_16x16x32_bf16(Ef[0][3], B3, a0h, 0,0,0);
        a1l = __builtin_amdgcn_mfma_f32_16x16x32_bf16(Ef[1][1], B1, a1l, 0,0,0);
        a1h = __builtin_amdgcn_mfma_f32_16x16x32_bf16(Ef[1][3], B3, a1h, 0,0,0);

        float o00 = (a0l[0]+a0h[0])*e0.x, o01 = (a0l[1]+a0h[1])*e0.y;
        float o02 = (a0l[2]+a0h[2])*e0.z, o03 = (a0l[3]+a0h[3])*e0.w;
        float o10 = (a1l[0]+a1h[0])*e1.x, o11 = (a1l[1]+a1h[1])*e1.y;
        float o12 = (a1l[2]+a1h[2])*e1.z, o13 = (a1l[3]+a1h[3])*e1.w;
        if (PH == 2) {
            o00*=invv; o01*=invv; o02*=invv; o03*=invv;
            o10*=invv; o11*=invv; o12*=invv; o13*=invv;
        }
        uint2 d0, d1;
        d0.x = cvt_pk(o00,o01); d0.y = cvt_pk(o02,o03);
        d1.x = cvt_pk(o10,o11); d1.y = cvt_pk(o12,o13);
        *(uint2*)(pwb + pwr[0]) = d0;
        *(uint2*)(pwb + pwr[1]) = d1;
    }
    asm volatile("s_waitcnt lgkmcnt(0)" ::: "memory");  // LDS visible; vmcnt stays in flight
    __builtin_amdgcn_s_barrier();
    asm volatile("" ::: "memory");
}

// emission prefetch (4-phase distance). fwd: t=ph (applied at step t);
// bwd: t=L-2-ph (output-side emission of bwd iteration ph). Clamped; unused when emit=0.
#define ISSUE(S0v, S1v, ph_) {                                   \
    int t_ = dir ? (L - 2 - (ph_)) : (ph_);                      \
    if (t_ < 0) t_ = 0; if (t_ >= L) t_ = L - 1;                 \
    const float* xp_ = Xb + (size_t)t_ * RN;                     \
    S0v = *(const float4*)(xp_ + o0);                            \
    S1v = *(const float4*)(xp_ + o1); }

// Bidirectional meet-in-the-middle: logZ = log(r_H^T p_{H-1}) + ls_f + ls_b.
// fwd: p_t = diag(eX_t) E p_{t-1}, H_f steps. bwd: u-chain with A = exp(trans)^T,
// u_{t} = eX_{t-1} (.) E^T u_{t+1}, init u_L = eX_{L-1} (.) endv, H_b steps,
// last step skips emission (raw r_H). Serial chain: 512 phases instead of 1024.
__global__ __launch_bounds__(512, 2)
void crf_nll_kernel(const float* __restrict__ X,
                    const int*   __restrict__ y,
                    const float* __restrict__ trans,
                    float* __restrict__ out, int L, int B)
{
    const int g    = blockIdx.x;
    const int tid  = threadIdx.x;
    const int w    = tid >> 6;
    const int dir  = w >> 2;        // 0 = forward, 1 = backward
    const int wl   = w & 3;         // tile-pair index within direction
    const int lane = tid & 63;
    const int c    = lane & 15;     // MFMA column = sequence
    const int q    = lane >> 4;     // k/row quad
    const int b0   = g * NSEQ;

    __shared__ __align__(16) char  pball[2][2*PHALF];   // [dir][buf]
    __shared__ float goldsh[NSEQ];
    __shared__ float lssh[2][NSEQ];

    int bseq = b0 + c; if (bseq >= B) bseq = B - 1;
    const float* Xb = X + (size_t)bseq * L * RN;
    const int*   yb = y + (size_t)bseq * L;

    const int Hf  = (L + 1) >> 1;      // fwd steps
    const int Hb  = L - Hf;            // bwd steps (<= Hf)
    const int NPH = Hf;                // phases

    // ---------------- init buffers ----------------
    if (tid < NSEQ) goldsh[tid] = 0.f;
    {
        int* pz = (int*)&pball[0][0];
        for (int i = tid; i < (4*PHALF)/4; i += 512) pz[i] = 0;
    }
    __syncthreads();
    if (tid < NSEQ)   // fwd p0[c][START] = 1.0, buffer 0
        *(unsigned short*)(&pball[0][0] + tid*PBS + 2*START_T) = (unsigned short)0x3F80;
    // bwd init u_L[c][s] = exp(trans[END,s] + X[c][L-1][s]), buffer 0
    for (int i = tid; i < NSEQ*RN; i += 512) {
        const int cc = i >> 7, s = i & 127;
        int b = b0 + cc; if (b >= B) b = B - 1;
        float v = __expf(trans[END_T*RN + s] + X[(size_t)b*L*RN + (size_t)(L-1)*RN + s]);
        *(unsigned short*)(&pball[1][0] + cc*PBS + 2*s) = f2bf(v);
    }

    // ---------------- gold path: 32 t-stripes (w,q) per seq ----------------
    {
        float gacc = 0.f;
        for (int t = 4*w + q; t < L; t += 32) {
            int yt = yb[t];
            int yp = t ? yb[t-1] : START_T;
            gacc += trans[yt*RN + yp] + Xb[(size_t)t*RN + yt];
        }
        if (w == 0 && q == 0) gacc += trans[END_T*RN + yb[L-1]];
        gacc += __shfl_xor(gacc, 16, 64);
        gacc += __shfl_xor(gacc, 32, 64);
        if (q == 0) atomicAdd(&goldsh[c], gacc);
    }

    // ---------------- Ef: permuted A-tiles. fwd: exp(trans); bwd: exp(trans)^T ----------------
    // tile T row m=c -> state 32(T&3) + 8(c>>2) + 4(T>>2) + (c&3)
    const int T0 = 2*wl, T1 = 2*wl + 1;
    v8s Ef[2][4];
    #pragma unroll
    for (int i = 0; i < 2; ++i) {
        const int T   = T0 + i;
        const int row = 32*(T&3) + 8*(c>>2) + 4*(T>>2) + (c&3);
        #pragma unroll
        for (int cc = 0; cc < 4; ++cc) {
            v8s v;
            if (dir == 0) {
                const float* tr = trans + (size_t)row*RN + 32*cc + 8*q;
                #pragma unroll
                for (int j = 0; j < 8; ++j) v[j] = (short)f2bf(__expf(tr[j]));
            } else {
                #pragma unroll
                for (int j = 0; j < 8; ++j)
                    v[j] = (short)f2bf(__expf(trans[(size_t)(32*cc + 8*q + j)*RN + row]));
            }
            Ef[i][cc] = v;
        }
    }

    // ---------------- LDS byte offsets ----------------
    char* pbase = &pball[dir][0];
    int prd[4], pwr[2];
    #pragma unroll
    for (int cc = 0; cc < 4; ++cc)
        prd[cc] = c*PBS + 64*cc + 16*q;                  // read k=32cc+8q (16B)
    pwr[0] = c*PBS + 64*(T0&3) + 8*(T0>>2) + 16*q;       // write 4-state runs (8B)
    pwr[1] = c*PBS + 64*(T1&3) + 8*(T1>>2) + 16*q;
    const int o0 = 32*(T0&3) + 4*(T0>>2) + 8*q;          // emission offsets (output states)
    const int o1 = 32*(T1&3) + 4*(T1>>2) + 8*q;

    __syncthreads();   // inits visible; only raw barriers from here (ring stays in flight)

    // ---------------- emission ring: 4 slots x 2 float4 ----------------
    float4 SA0,SA1, SB0,SB1, SC0,SC1, SD0,SD1;
    ISSUE(SA0,SA1, 0) ISSUE(SB0,SB1, 1) ISSUE(SC0,SC1, 2) ISSUE(SD0,SD1, 3)

    float logscale = 0.f, mxf = 1.f, invv = 1.f;
    const int mysteps = dir ? Hb : Hf;

    // main loop: phases [0, 4*nq) — all act && emit for both directions
    const int nq = (Hb >= 1) ? (Hb - 1) / 4 : 0;
    for (int tt = 0; tt < 4*nq; tt += 4) {
        stepf<0>(Ef, pbase,         pbase + PHALF, prd, pwr, SA0, SA1, true, true, logscale, mxf, invv);
        ISSUE(SA0,SA1, tt + 4)
        stepf<1>(Ef, pbase + PHALF, pbase,         prd, pwr, SB0, SB1, true, true, logscale, mxf, invv);
        ISSUE(SB0,SB1, tt + 5)
        stepf<2>(Ef, pbase,         pbase + PHALF, prd, pwr, SC0, SC1, true, true, logscale, mxf, invv);
        ISSUE(SC0,SC1, tt + 6)
        stepf<3>(Ef, pbase + PHALF, pbase,         prd, pwr, SD0, SD1, true, true, logscale, mxf, invv);
        ISSUE(SD0,SD1, tt + 7)
    }
    // tail phases: predicated act/emit (bwd last step skips emission; odd-L idle phases)
    for (int ph = 4*nq; ph < NPH; ++ph) {
        const bool act  = ph < mysteps;
        const bool emit = (dir == 0) || (ph != Hb - 1);
        float4 s0, s1;
        s0.x=s0.y=s0.z=s0.w=0.f; s1 = s0;
        if (act && emit) {
            int te = dir ? (L - 2 - ph) : ph;
            if (te < 0) te = 0; if (te >= L) te = L - 1;
            s0 = *(const float4*)(Xb + (size_t)te*RN + o0);
            s1 = *(const float4*)(Xb + (size_t)te*RN + o1);
        }
        char* prb_ = pbase + (ph & 1)*PHALF;
        char* pwb_ = pbase + ((ph + 1) & 1)*PHALF;
        switch (ph & 3) {
            case 0:  stepf<0>(Ef, prb_, pwb_, prd, pwr, s0, s1, act, emit, logscale, mxf, invv); break;
            case 1:  stepf<1>(Ef, prb_, pwb_, prd, pwr, s0, s1, act, emit, logscale, mxf, invv); break;
            case 2:  stepf<2>(Ef, prb_, pwb_, prd, pwr, s0, s1, act, emit, logscale, mxf, invv); break;
            default: stepf<3>(Ef, prb_, pwb_, prd, pwr, s0, s1, act, emit, logscale, mxf, invv); break;
        }
    }

    // ---------------- combine: logZ = ls_f + ls_b + log(p_F . r_B) ----------------
    if (wl == 0 && q == 0) lssh[dir][c] = logscale;
    __syncthreads();

    if (w == 0) {
        char* pF = &pball[0][0] + (Hf & 1)*PHALF;
        char* pB = &pball[1][0] + (Hb & 1)*PHALF;
        float dot = 0.f;
        #pragma unroll
        for (int cc = 0; cc < 4; ++cc) {
            v8s a = *(const v8s*)(pF + prd[cc]);
            v8s b = *(const v8s*)(pB + prd[cc]);
            #pragma unroll
            for (int j = 0; j < 8; ++j)
                dot += bf2f((unsigned short)a[j]) * bf2f((unsigned short)b[j]);
        }
        dot += __shfl_xor(dot, 16, 64);
        dot += __shfl_xor(dot, 32, 64);
        if (q == 0 && (b0 + c) < B)
            out[b0 + c] = lssh[0][c] + lssh[1][c] + __logf(dot) - goldsh[c];
    }
}

extern "C" void kernel_launch(void* const* d_in, const int* in_sizes, int n_in,
                              void* d_out, int out_size, void* d_ws, size_t ws_size,
                              hipStream_t stream) {
    const float* X     = (const float*)d_in[0];
    const int*   y     = (const int*)d_in[1];
    const float* trans = (const float*)d_in[2];
    float*       out   = (float*)d_out;

    const int B = out_size;            // 256
    const int L = in_sizes[1] / B;     // 1024

    const int blocks = (B + NSEQ - 1) / NSEQ;   // 16
    crf_nll_kernel<<<dim3(blocks), dim3(512), 0, stream>>>(X, y, trans, out, L, B);
}

// Round 6
// 453.248 us; speedup vs baseline: 2.8949x; 1.2990x over previous
//
#include <hip/hip_runtime.h>

#define RN      128
#define START_T 126
#define END_T   127
#define NSEQ    16
#define PBS     272              // pbuf row stride (bytes)
#define PHALF   (NSEQ*PBS)       // one p buffer (4352 B)

typedef short v8s __attribute__((ext_vector_type(8)));   // 8 x bf16 MFMA A/B frag
typedef float v4f __attribute__((ext_vector_type(4)));   // 4 x f32 MFMA C/D frag

__device__ __forceinline__ unsigned short f2bf(float f){
    unsigned u = __float_as_uint(f);
    u += 0x7fffu + ((u>>16)&1u);
    return (unsigned short)(u>>16);
}
__device__ __forceinline__ float bf2f(unsigned short s){
    return __uint_as_float(((unsigned)s)<<16);
}
__device__ __forceinline__ unsigned cvt_pk(float lo, float hi){
    unsigned r;
    asm("v_cvt_pk_bf16_f32 %0, %1, %2" : "=v"(r) : "v"(lo), "v"(hi));
    return r;
}
__device__ __forceinline__ unsigned pkmax_u16(unsigned a, unsigned b){
    unsigned r;
    asm("v_pk_max_u16 %0, %1, %2" : "=v"(r) : "v"(a), "v"(b));
    return r;
}
__device__ __forceinline__ float4 exp4(float4 v){
    float4 e; e.x=__expf(v.x); e.y=__expf(v.y); e.z=__expf(v.z); e.w=__expf(v.w); return e;
}

// One step. 4 waves/block (1/SIMD), wave w owns tiles {2w,2w+1}; 8 MFMAs/wave.
// Permuted-A: tile T row m=c -> state 32(T&3)+8q+4(T>>2)+(reg i): outputs are two
// aligned 4-state runs of the B layout -> 2x ds_write_b64, reads 4x ds_read_b128.
// Barrier = lgkmcnt(0)+s_barrier only: global emission ring stays in flight.
// (Round-5 lesson: do NOT share this barrier/LDS across directions - 8-wave
// lockstep doubles per-phase cost. Directions live in separate blocks now.)
template<int PH>
__device__ __forceinline__ void stepf(const v8s (&Ef)[2][4],
                                      char* prb, char* pwb,
                                      const int (&prd)[4], const int (&pwr)[2],
                                      const float4& S0, const float4& S1,
                                      bool emit,
                                      float& logscale, float& mxf, float& invv)
{
    v8s B0 = *(const v8s*)(prb + prd[0]);
    v8s B1 = *(const v8s*)(prb + prd[1]);
    v8s B2 = *(const v8s*)(prb + prd[2]);
    v8s B3 = *(const v8s*)(prb + prd[3]);

    if (PH == 1) {   // per-seq max over the B view (lane (c,q): 32 vals; quads via shfl)
        union U8 { v8s v; unsigned u[4]; };
        U8 ua, ub, uc, ud; ua.v = B0; ub.v = B1; uc.v = B2; ud.v = B3;
        unsigned m0 = pkmax_u16(ua.u[0], ua.u[1]);
        unsigned m1 = pkmax_u16(ua.u[2], ua.u[3]);
        unsigned m2 = pkmax_u16(ub.u[0], ub.u[1]);
        unsigned m3 = pkmax_u16(ub.u[2], ub.u[3]);
        unsigned m4 = pkmax_u16(uc.u[0], uc.u[1]);
        unsigned m5 = pkmax_u16(uc.u[2], uc.u[3]);
        unsigned m6 = pkmax_u16(ud.u[0], ud.u[1]);
        unsigned m7 = pkmax_u16(ud.u[2], ud.u[3]);
        m0 = pkmax_u16(m0, m1); m2 = pkmax_u16(m2, m3);
        m4 = pkmax_u16(m4, m5); m6 = pkmax_u16(m6, m7);
        m0 = pkmax_u16(m0, m2); m4 = pkmax_u16(m4, m6);
        m0 = pkmax_u16(m0, m4);
        unsigned lo = m0 & 0xffffu, hi = m0 >> 16;
        unsigned mm = (lo > hi) ? lo : hi;     // bf16 >= 0: bit order == value order
        float f = __uint_as_float(mm << 16);
        f = fmaxf(f, __shfl_xor(f, 16, 64));
        f = fmaxf(f, __shfl_xor(f, 32, 64));
        mxf = f;
    }
    if (PH == 2) { invv = 1.0f / mxf; logscale += __logf(mxf); }

    float4 e0, e1;
    if (emit) { e0 = exp4(S0); e1 = exp4(S1); }
    else      { e0.x=e0.y=e0.z=e0.w=1.f; e1 = e0; }   // bwd final step: raw r

    v4f a0l = {0.f,0.f,0.f,0.f}, a0h = {0.f,0.f,0.f,0.f};
    v4f a1l = {0.f,0.f,0.f,0.f}, a1h = {0.f,0.f,0.f,0.f};
    a0l = __builtin_amdgcn_mfma_f32_16x16x32_bf16(Ef[0][0], B0, a0l, 0,0,0);
    a0h = __builtin_amdgcn_mfma_f32_16x16x32_bf16(Ef[0][2], B2, a0h, 0,0,0);
    a1l = __builtin_amdgcn_mfma_f32_16x16x32_bf16(Ef[1][0], B0, a1l, 0,0,0);
    a1h = __builtin_amdgcn_mfma_f32_16x16x32_bf16(Ef[1][2], B2, a1h, 0,0,0);
    a0l = __builtin_amdgcn_mfma_f32_16x16x32_bf16(Ef[0][1], B1, a0l, 0,0,0);
    a0h = __builtin_amdgcn_mfma_f32_16x16x32_bf16(Ef[0][3], B3, a0h, 0,0,0);
    a1l = __builtin_amdgcn_mfma_f32_16x16x32_bf16(Ef[1][1], B1, a1l, 0,0,0);
    a1h = __builtin_amdgcn_mfma_f32_16x16x32_bf16(Ef[1][3], B3, a1h, 0,0,0);

    float o00 = (a0l[0]+a0h[0])*e0.x, o01 = (a0l[1]+a0h[1])*e0.y;
    float o02 = (a0l[2]+a0h[2])*e0.z, o03 = (a0l[3]+a0h[3])*e0.w;
    float o10 = (a1l[0]+a1h[0])*e1.x, o11 = (a1l[1]+a1h[1])*e1.y;
    float o12 = (a1l[2]+a1h[2])*e1.z, o13 = (a1l[3]+a1h[3])*e1.w;
    if (PH == 2) {
        o00*=invv; o01*=invv; o02*=invv; o03*=invv;
        o10*=invv; o11*=invv; o12*=invv; o13*=invv;
    }
    uint2 d0, d1;
    d0.x = cvt_pk(o00,o01); d0.y = cvt_pk(o02,o03);
    d1.x = cvt_pk(o10,o11); d1.y = cvt_pk(o12,o13);
    *(uint2*)(pwb + pwr[0]) = d0;
    *(uint2*)(pwb + pwr[1]) = d1;

    asm volatile("s_waitcnt lgkmcnt(0)" ::: "memory");  // LDS visible; vmcnt stays in flight
    __builtin_amdgcn_s_barrier();
    asm volatile("" ::: "memory");
}

// emission prefetch (4-phase distance). fwd: t=ph; bwd: t=L-2-ph (output-side).
#define ISSUE(S0v, S1v, ph_) {                                   \
    int t_ = dir ? (L - 2 - (ph_)) : (ph_);                      \
    if (t_ < 0) t_ = 0; if (t_ >= L) t_ = L - 1;                 \
    const float* xp_ = Xb + (size_t)t_ * RN;                     \
    S0v = *(const float4*)(xp_ + o0);                            \
    S1v = *(const float4*)(xp_ + o1); }

// Blocks [0,ngp): forward chain (Hf steps). Blocks [ngp,2*ngp): backward chain
// (Hb steps, A = exp(trans)^T, emissions applied output-side, last step raw).
// Each block: round-4 structure exactly (4 waves, private LDS + barrier).
// Results staged to ws; combine kernel does logZ = ls_f+ls_b+log(pF.rB)-gold.
__global__ __launch_bounds__(256, 1)
void crf_fb_kernel(const float* __restrict__ X,
                   const int*   __restrict__ y,
                   const float* __restrict__ trans,
                   char* __restrict__ ws, int L, int B, int ngp)
{
    const int blk  = blockIdx.x;
    const int dir  = (blk >= ngp) ? 1 : 0;
    const int g    = dir ? blk - ngp : blk;
    const int tid  = threadIdx.x;
    const int w    = tid >> 6;
    const int lane = tid & 63;
    const int c    = lane & 15;     // MFMA column = sequence
    const int q    = lane >> 4;     // k/row quad
    const int b0   = g * NSEQ;

    __shared__ __align__(16) char  pb[2*PHALF];
    __shared__ float goldsh[NSEQ];

    int bseq = b0 + c; if (bseq >= B) bseq = B - 1;
    const float* Xb = X + (size_t)bseq * L * RN;
    const int*   yb = y + (size_t)bseq * L;

    const int Hf    = (L + 1) >> 1;
    const int Hb    = L - Hf;
    const int steps = dir ? Hb : Hf;

    // ---------------- init ----------------
    if (tid < NSEQ) goldsh[tid] = 0.f;
    {
        int* pz = (int*)pb;
        for (int i = tid; i < (2*PHALF)/4; i += 256) pz[i] = 0;
    }
    __syncthreads();
    if (dir == 0) {
        if (tid < NSEQ)   // p0[c][START] = 1.0, buffer 0
            *(unsigned short*)(pb + tid*PBS + 2*START_T) = (unsigned short)0x3F80;
    } else {
        // u_L[c][s] = exp(trans[END,s] + X[c][L-1][s]), buffer 0
        for (int i = tid; i < NSEQ*RN; i += 256) {
            const int cc = i >> 7, s = i & 127;
            int b = b0 + cc; if (b >= B) b = B - 1;
            float v = __expf(trans[END_T*RN + s] + X[(size_t)b*L*RN + (size_t)(L-1)*RN + s]);
            *(unsigned short*)(pb + cc*PBS + 2*s) = f2bf(v);
        }
    }

    // ---------------- gold (split): fwd t in [0,Hf), bwd t in [Hf,L) ----------------
    {
        float gacc = 0.f;
        const int tlo = dir ? Hf : 0;
        const int thi = dir ? L  : Hf;
        for (int t = tlo + 4*w + q; t < thi; t += 16) {
            int yt = yb[t];
            int yp = t ? yb[t-1] : START_T;
            gacc += trans[yt*RN + yp] + Xb[(size_t)t*RN + yt];
        }
        if (dir == 1 && w == 0 && q == 0) gacc += trans[END_T*RN + yb[L-1]];
        gacc += __shfl_xor(gacc, 16, 64);
        gacc += __shfl_xor(gacc, 32, 64);
        if (q == 0) atomicAdd(&goldsh[c], gacc);
    }

    // ---------------- Ef: permuted A-tiles. fwd: exp(trans); bwd: exp(trans)^T ----------------
    const int T0 = 2*w, T1 = 2*w + 1;
    v8s Ef[2][4];
    #pragma unroll
    for (int i = 0; i < 2; ++i) {
        const int T   = T0 + i;
        const int row = 32*(T&3) + 8*(c>>2) + 4*(T>>2) + (c&3);
        #pragma unroll
        for (int cc = 0; cc < 4; ++cc) {
            v8s v;
            if (dir == 0) {
                const float* tr = trans + (size_t)row*RN + 32*cc + 8*q;
                #pragma unroll
                for (int j = 0; j < 8; ++j) v[j] = (short)f2bf(__expf(tr[j]));
            } else {
                #pragma unroll
                for (int j = 0; j < 8; ++j)
                    v[j] = (short)f2bf(__expf(trans[(size_t)(32*cc + 8*q + j)*RN + row]));
            }
            Ef[i][cc] = v;
        }
    }

    // ---------------- LDS byte offsets ----------------
    int prd[4], pwr[2];
    #pragma unroll
    for (int cc = 0; cc < 4; ++cc)
        prd[cc] = c*PBS + 64*cc + 16*q;                  // read k=32cc+8q (16B)
    pwr[0] = c*PBS + 64*(T0&3) + 8*(T0>>2) + 16*q;       // write 4-state runs (8B)
    pwr[1] = c*PBS + 64*(T1&3) + 8*(T1>>2) + 16*q;
    const int o0 = 32*(T0&3) + 4*(T0>>2) + 8*q;          // emission offsets (output states)
    const int o1 = 32*(T1&3) + 4*(T1>>2) + 8*q;

    __syncthreads();   // inits visible; only raw barriers from here

    // ---------------- emission ring: 4 slots x 2 float4 ----------------
    float4 SA0,SA1, SB0,SB1, SC0,SC1, SD0,SD1;
    ISSUE(SA0,SA1, 0) ISSUE(SB0,SB1, 1) ISSUE(SC0,SC1, 2) ISSUE(SD0,SD1, 3)

    float logscale = 0.f, mxf = 1.f, invv = 1.f;

    // main loop: all-emit phases (bwd excludes its final no-emit step)
    const int full = (steps - dir) & ~3;
    for (int tt = 0; tt < full; tt += 4) {
        stepf<0>(Ef, pb,         pb + PHALF, prd, pwr, SA0, SA1, true, logscale, mxf, invv);
        ISSUE(SA0,SA1, tt + 4)
        stepf<1>(Ef, pb + PHALF, pb,         prd, pwr, SB0, SB1, true, logscale, mxf, invv);
        ISSUE(SB0,SB1, tt + 5)
        stepf<2>(Ef, pb,         pb + PHALF, prd, pwr, SC0, SC1, true, logscale, mxf, invv);
        ISSUE(SC0,SC1, tt + 6)
        stepf<3>(Ef, pb + PHALF, pb,         prd, pwr, SD0, SD1, true, logscale, mxf, invv);
        ISSUE(SD0,SD1, tt + 7)
    }
    // tail: remaining phases; bwd's last step skips emission
    for (int ph = full; ph < steps; ++ph) {
        const bool emit = (dir == 0) || (ph != steps - 1);
        float4 s0, s1;
        s0.x=s0.y=s0.z=s0.w=0.f; s1 = s0;
        if (emit) {
            int te = dir ? (L - 2 - ph) : ph;
            if (te < 0) te = 0; if (te >= L) te = L - 1;
            s0 = *(const float4*)(Xb + (size_t)te*RN + o0);
            s1 = *(const float4*)(Xb + (size_t)te*RN + o1);
        }
        char* prb_ = pb + (ph & 1)*PHALF;
        char* pwb_ = pb + ((ph + 1) & 1)*PHALF;
        switch (ph & 3) {
            case 0:  stepf<0>(Ef, prb_, pwb_, prd, pwr, s0, s1, emit, logscale, mxf, invv); break;
            case 1:  stepf<1>(Ef, prb_, pwb_, prd, pwr, s0, s1, emit, logscale, mxf, invv); break;
            case 2:  stepf<2>(Ef, prb_, pwb_, prd, pwr, s0, s1, emit, logscale, mxf, invv); break;
            default: stepf<3>(Ef, prb_, pwb_, prd, pwr, s0, s1, emit, logscale, mxf, invv); break;
        }
    }

    // ---------------- stage results to ws ----------------
    // layout: [0, PV): pF bf16[ngp*16*128]; [PV, 2PV): rB; then 4 float arrays
    // of ngp*16: lsf, lsb, goldf, goldb.
    const size_t PV = (size_t)ngp * NSEQ * RN * sizeof(unsigned short);
    char* pf = pb + (steps & 1)*PHALF;
    if (w == 0) {
        unsigned short* prow = (unsigned short*)(ws + (size_t)dir*PV)
                             + (size_t)(g*NSEQ + c)*RN;
        #pragma unroll
        for (int cc = 0; cc < 4; ++cc) {
            v8s pv = *(const v8s*)(pf + prd[cc]);     // lane holds states 32cc+8q+j
            *(v8s*)(prow + 32*cc + 8*q) = pv;
        }
        if (q == 0) {
            float* fbase = (float*)(ws + 2*PV);
            const int N = ngp*NSEQ, i = g*NSEQ + c;
            fbase[(size_t)dir*N + i]       = logscale;   // lsf / lsb
            fbase[(size_t)(2+dir)*N + i]   = goldsh[c];  // goldf / goldb
        }
    }
}

__global__ __launch_bounds__(64, 1)
void crf_combine(const char* __restrict__ ws, float* __restrict__ out, int B, int ngp)
{
    const int g    = blockIdx.x;
    const int lane = threadIdx.x & 63;
    const int c    = lane & 15;
    const int q    = lane >> 4;
    const int b0   = g * NSEQ;

    const size_t PV = (size_t)ngp * NSEQ * RN * sizeof(unsigned short);
    const unsigned short* pF = (const unsigned short*)ws        + (size_t)(g*NSEQ + c)*RN;
    const unsigned short* rB = (const unsigned short*)(ws + PV) + (size_t)(g*NSEQ + c)*RN;

    float dot = 0.f;
    #pragma unroll
    for (int u = 0; u < 4; ++u) {
        v8s a = *(const v8s*)(pF + 32*q + 8*u);
        v8s b = *(const v8s*)(rB + 32*q + 8*u);
        #pragma unroll
        for (int j = 0; j < 8; ++j)
            dot += bf2f((unsigned short)a[j]) * bf2f((unsigned short)b[j]);
    }
    dot += __shfl_xor(dot, 16, 64);
    dot += __shfl_xor(dot, 32, 64);

    if (q == 0 && (b0 + c) < B) {
        const float* fbase = (const float*)(ws + 2*PV);
        const int N = ngp*NSEQ, i = g*NSEQ + c;
        out[b0 + c] = fbase[i] + fbase[N + i] + __logf(dot)
                    - fbase[2*N + i] - fbase[3*N + i];
    }
}

extern "C" void kernel_launch(void* const* d_in, const int* in_sizes, int n_in,
                              void* d_out, int out_size, void* d_ws, size_t ws_size,
                              hipStream_t stream) {
    const float* X     = (const float*)d_in[0];
    const int*   y     = (const int*)d_in[1];
    const float* trans = (const float*)d_in[2];
    float*       out   = (float*)d_out;

    const int B = out_size;            // 256
    const int L = in_sizes[1] / B;     // 1024

    const int ngp = (B + NSEQ - 1) / NSEQ;   // 16
    crf_fb_kernel<<<dim3(2*ngp), dim3(256), 0, stream>>>(X, y, trans,
                                                         (char*)d_ws, L, B, ngp);
    crf_combine<<<dim3(ngp), dim3(64), 0, stream>>>((const char*)d_ws, out, B, ngp);
}